// Round 1
// baseline (328.151 us; speedup 1.0000x reference)
//
#include <hip/hip_runtime.h>

#define D 512
#define E 8
#define H 128
#define TM 16

// ---------------- K1: router — one wave per token ----------------
__global__ void k_router(const float* __restrict__ x, const float* __restrict__ Wr,
                         const float* __restrict__ br, int* __restrict__ tokE,
                         float* __restrict__ confPart) {
  const int lane = threadIdx.x & 63;
  const int wave = threadIdx.x >> 6;
  const int token = blockIdx.x * 4 + wave;

  // each lane owns Wr rows [lane*8 .. lane*8+7] (8 floats each) in registers
  float wr[8][8];
  const float4* wrp = reinterpret_cast<const float4*>(Wr) + lane * 16;
#pragma unroll
  for (int j = 0; j < 8; ++j) {
    float4 a = wrp[j * 2 + 0];
    float4 b = wrp[j * 2 + 1];
    wr[j][0] = a.x; wr[j][1] = a.y; wr[j][2] = a.z; wr[j][3] = a.w;
    wr[j][4] = b.x; wr[j][5] = b.y; wr[j][6] = b.z; wr[j][7] = b.w;
  }

  const float4* xp = reinterpret_cast<const float4*>(x + (size_t)token * D + lane * 8);
  float4 x0 = xp[0], x1 = xp[1];
  float xv[8] = {x0.x, x0.y, x0.z, x0.w, x1.x, x1.y, x1.z, x1.w};

  float acc[E] = {0, 0, 0, 0, 0, 0, 0, 0};
#pragma unroll
  for (int j = 0; j < 8; ++j)
#pragma unroll
    for (int e = 0; e < E; ++e)
      acc[e] += xv[j] * wr[j][e];

#pragma unroll
  for (int m = 1; m < 64; m <<= 1)
#pragma unroll
    for (int e = 0; e < E; ++e)
      acc[e] += __shfl_xor(acc[e], m, 64);

  __shared__ float cf[4];
  if (lane == 0) {
#pragma unroll
    for (int e = 0; e < E; ++e) acc[e] += br[e];
    int e0 = 0; float v0 = acc[0];
#pragma unroll
    for (int e = 1; e < E; ++e) if (acc[e] > v0) { v0 = acc[e]; e0 = e; }
    int e1 = -1; float v1 = -1e30f;
#pragma unroll
    for (int e = 0; e < E; ++e) if (e != e0 && acc[e] > v1) { v1 = acc[e]; e1 = e; }
    tokE[token * 2 + 0] = e0;
    tokE[token * 2 + 1] = e1;
    cf[wave] = v0;
  }
  __syncthreads();
  if (threadIdx.x == 0) confPart[blockIdx.x] = cf[0] + cf[1] + cf[2] + cf[3];
}

// ---------------- K2: per-chunk (256 tokens) expert counts ----------------
__global__ void k_count(const int* __restrict__ tokE, int* __restrict__ chunkCnt) {
  __shared__ int c[E];
  if (threadIdx.x < E) c[threadIdx.x] = 0;
  __syncthreads();
  int token = blockIdx.x * 256 + threadIdx.x;
  atomicAdd(&c[tokE[token * 2 + 0]], 1);
  atomicAdd(&c[tokE[token * 2 + 1]], 1);
  __syncthreads();
  if (threadIdx.x < E) chunkCnt[blockIdx.x * E + threadIdx.x] = c[threadIdx.x];
}

// ---------------- K3: scan chunks, stats tail ----------------
__global__ void k_scan(const int* __restrict__ chunkCnt, const float* __restrict__ confPart,
                       int* __restrict__ chunkOff, int* __restrict__ kept,
                       float* __restrict__ outTail, int nConf, int nChunks, int cap, int nTok) {
  if (threadIdx.x < E) {
    int off = 0;
    for (int c = 0; c < nChunks; ++c) {
      chunkOff[c * E + threadIdx.x] = off;
      off += chunkCnt[c * E + threadIdx.x];
    }
    kept[threadIdx.x] = min(off, cap);
  }
  __shared__ float s[256];
  float a = 0.f;
  for (int i = threadIdx.x; i < nConf; i += 256) a += confPart[i];
  s[threadIdx.x] = a;
  __syncthreads();
  for (int st = 128; st > 0; st >>= 1) {
    if (threadIdx.x < st) s[threadIdx.x] += s[threadIdx.x + st];
    __syncthreads();
  }
  if (threadIdx.x == 0) {
    float tot = 0.f, ld[E];
    for (int e = 0; e < E; ++e) { ld[e] = (float)kept[e]; tot += ld[e]; }
    float denom = tot + 1e-8f;
    float loss = 0.f;
    float dist[E];
    for (int e = 0; e < E; ++e) {
      dist[e] = ld[e] / denom;
      loss += dist[e] * logf(dist[e] + 1e-8f);
    }
    outTail[0] = loss;
    for (int e = 0; e < E; ++e) outTail[1 + e] = dist[e];
    outTail[1 + E] = s[0] / (float)nTok;
  }
}

// ---------------- K4: in-order rank assignment + dispatch lists ----------------
__global__ void k_dispatch(const int* __restrict__ tokE, const int* __restrict__ chunkOff,
                           int* __restrict__ expList, int cap) {
  const int lane = threadIdx.x & 63;
  const int wave = threadIdx.x >> 6;
  const int token = blockIdx.x * 256 + threadIdx.x;
  const int e0 = tokE[token * 2 + 0];
  const int e1 = tokE[token * 2 + 1];
  __shared__ int wcnt[4][E];
  unsigned long long lt = (lane == 63) ? 0x7fffffffffffffffull : ((1ull << lane) - 1ull);
  int r0 = 0, r1 = 0;
#pragma unroll
  for (int e = 0; e < E; ++e) {
    unsigned long long b0 = __ballot(e0 == e);
    unsigned long long b1 = __ballot(e1 == e);
    unsigned long long m = b0 | b1;
    if (e0 == e) r0 = __popcll(m & lt);
    if (e1 == e) r1 = __popcll(m & lt);
    if (lane == 0) wcnt[wave][e] = __popcll(m);
  }
  __syncthreads();
  int base0 = chunkOff[blockIdx.x * E + e0];
  int base1 = chunkOff[blockIdx.x * E + e1];
  for (int w = 0; w < wave; ++w) {
    base0 += wcnt[w][e0];
    base1 += wcnt[w][e1];
  }
  int g0 = base0 + r0;
  int g1 = base1 + r1;
  if (g0 < cap) expList[e0 * cap + g0] = token;
  if (g1 < cap) expList[e1 * cap + g1] = token;
}

// ---------------- K5: per-expert 2-layer FFN, atomic combine ----------------
__global__ void k_expert(const float* __restrict__ x, const float* __restrict__ W1,
                         const float* __restrict__ b1, const float* __restrict__ W2,
                         const float* __restrict__ b2, const int* __restrict__ expList,
                         const int* __restrict__ kept, float* __restrict__ out, int cap) {
  const int e = blockIdx.y;
  const int cnt = kept[e];
  const int t0 = blockIdx.x * TM;
  if (t0 >= cnt) return;
  const int nt = min(TM, cnt - t0);

  __shared__ float xs[TM][D];
  __shared__ float hs[TM][H + 1];
  __shared__ int toks[TM];

  if (threadIdx.x < TM)
    toks[threadIdx.x] = (threadIdx.x < nt) ? expList[e * cap + t0 + threadIdx.x] : -1;
  __syncthreads();

  // stage x rows (float4, coalesced)
#pragma unroll
  for (int k = 0; k < (TM * D / 4) / 256; ++k) {
    int idx = threadIdx.x + k * 256;
    int r = idx >> 7;          // 128 float4 per row
    int c4 = idx & 127;
    float4 v = (r < nt) ? reinterpret_cast<const float4*>(x + (size_t)toks[r] * D)[c4]
                        : make_float4(0.f, 0.f, 0.f, 0.f);
    reinterpret_cast<float4*>(xs[r])[c4] = v;
  }
  __syncthreads();

  // phase 1: h = relu(x @ W1 + b1)
  const int hcol = threadIdx.x & (H - 1);
  const int grp = threadIdx.x >> 7;      // 0..1 -> tokens grp*8 .. grp*8+7
  float hacc[TM / 2];
#pragma unroll
  for (int i = 0; i < TM / 2; ++i) hacc[i] = 0.f;
  const float* w1p = W1 + (size_t)e * D * H + hcol;
  for (int d = 0; d < D; ++d) {
    float w = w1p[(size_t)d * H];
#pragma unroll
    for (int i = 0; i < TM / 2; ++i) hacc[i] += xs[grp * (TM / 2) + i][d] * w;
  }
  float bb = b1[e * H + hcol];
#pragma unroll
  for (int i = 0; i < TM / 2; ++i)
    hs[grp * (TM / 2) + i][hcol] = fmaxf(hacc[i] + bb, 0.f);
  __syncthreads();

  // phase 2: y = h @ W2 + b2 ; atomic combine into out
  float ya[TM], yb[TM];
#pragma unroll
  for (int i = 0; i < TM; ++i) { ya[i] = 0.f; yb[i] = 0.f; }
  const float* w2p = W2 + (size_t)e * H * D;
  const int dc = threadIdx.x;            // cols dc and dc+256
  for (int hh = 0; hh < H; ++hh) {
    float w0 = w2p[(size_t)hh * D + dc];
    float w1w = w2p[(size_t)hh * D + dc + 256];
#pragma unroll
    for (int i = 0; i < TM; ++i) {
      float hv = hs[i][hh];
      ya[i] += hv * w0;
      yb[i] += hv * w1w;
    }
  }
  float bA = b2[e * D + dc], bB = b2[e * D + dc + 256];
  for (int i = 0; i < nt; ++i) {
    atomicAdd(&out[(size_t)toks[i] * D + dc], ya[i] + bA);
    atomicAdd(&out[(size_t)toks[i] * D + dc + 256], yb[i] + bB);
  }
}

extern "C" void kernel_launch(void* const* d_in, const int* in_sizes, int n_in,
                              void* d_out, int out_size, void* d_ws, size_t ws_size,
                              hipStream_t stream) {
  const float* x  = (const float*)d_in[0];
  const float* Wr = (const float*)d_in[1];
  const float* br = (const float*)d_in[2];
  const float* W1 = (const float*)d_in[3];
  const float* b1 = (const float*)d_in[4];
  const float* W2 = (const float*)d_in[5];
  const float* b2 = (const float*)d_in[6];
  float* out = (float*)d_out;

  const int N = in_sizes[0] / D;                 // 32768
  const int cap = (int)(1.25f * (float)(N / E)); // 5120
  const int chunks = N / 256;                    // 128

  int* tokE = (int*)d_ws;
  float* confPart = (float*)(tokE + (size_t)N * 2);
  int* chunkCnt = (int*)(confPart + N / 4);
  int* chunkOff = chunkCnt + chunks * E;
  int* kept = chunkOff + chunks * E;
  int* expList = kept + E;

  hipMemsetAsync(d_out, 0, (size_t)N * D * sizeof(float), stream);

  k_router<<<N / 4, 256, 0, stream>>>(x, Wr, br, tokE, confPart);
  k_count<<<chunks, 256, 0, stream>>>(tokE, chunkCnt);
  k_scan<<<1, 256, 0, stream>>>(chunkCnt, confPart, chunkOff, kept,
                                out + (size_t)N * D, N / 4, chunks, cap, N);
  k_dispatch<<<chunks, 256, 0, stream>>>(tokE, chunkOff, expList, cap);

  const int tiles = (cap + TM - 1) / TM;
  dim3 g5(tiles, E);
  k_expert<<<g5, 256, 0, stream>>>(x, W1, b1, W2, b2, expList, kept, out, cap);
}

// Round 3
// 243.860 us; speedup vs baseline: 1.3457x; 1.3457x over previous
//
#include <hip/hip_runtime.h>

#define D 512
#define E 8
#define H 128
#define BM 64
#define HP 136   // padded LDS row stride for h (shorts): 272B -> 2-way bank aliasing (free)

typedef __attribute__((ext_vector_type(8))) short short8v;
typedef __attribute__((ext_vector_type(4))) float float4v;

__device__ inline short f2bf(float f) {
  union { float f; unsigned u; } v; v.f = f;
  unsigned r = v.u + 0x7fffu + ((v.u >> 16) & 1u);   // round-to-nearest-even
  return (short)(r >> 16);
}

// ---------------- K1: router — one wave per token (fp32 exact) ----------------
__global__ void k_router(const float* __restrict__ x, const float* __restrict__ Wr,
                         const float* __restrict__ br, int* __restrict__ tokE,
                         float* __restrict__ confPart) {
  const int lane = threadIdx.x & 63;
  const int wave = threadIdx.x >> 6;
  const int token = blockIdx.x * 4 + wave;

  float wr[8][8];
  const float4* wrp = reinterpret_cast<const float4*>(Wr) + lane * 16;
#pragma unroll
  for (int j = 0; j < 8; ++j) {
    float4 a = wrp[j * 2 + 0];
    float4 b = wrp[j * 2 + 1];
    wr[j][0] = a.x; wr[j][1] = a.y; wr[j][2] = a.z; wr[j][3] = a.w;
    wr[j][4] = b.x; wr[j][5] = b.y; wr[j][6] = b.z; wr[j][7] = b.w;
  }

  const float4* xp = reinterpret_cast<const float4*>(x + (size_t)token * D + lane * 8);
  float4 x0 = xp[0], x1 = xp[1];
  float xv[8] = {x0.x, x0.y, x0.z, x0.w, x1.x, x1.y, x1.z, x1.w};

  float acc[E] = {0, 0, 0, 0, 0, 0, 0, 0};
#pragma unroll
  for (int j = 0; j < 8; ++j)
#pragma unroll
    for (int e = 0; e < E; ++e)
      acc[e] += xv[j] * wr[j][e];

#pragma unroll
  for (int m = 1; m < 64; m <<= 1)
#pragma unroll
    for (int e = 0; e < E; ++e)
      acc[e] += __shfl_xor(acc[e], m, 64);

  __shared__ float cf[4];
  if (lane == 0) {
#pragma unroll
    for (int e = 0; e < E; ++e) acc[e] += br[e];
    int e0 = 0; float v0 = acc[0];
#pragma unroll
    for (int e = 1; e < E; ++e) if (acc[e] > v0) { v0 = acc[e]; e0 = e; }
    int e1 = -1; float v1 = -1e30f;
#pragma unroll
    for (int e = 0; e < E; ++e) if (e != e0 && acc[e] > v1) { v1 = acc[e]; e1 = e; }
    tokE[token * 2 + 0] = e0;
    tokE[token * 2 + 1] = e1;
    cf[wave] = v0;
  }
  __syncthreads();
  if (threadIdx.x == 0) confPart[blockIdx.x] = cf[0] + cf[1] + cf[2] + cf[3];
}

// ---------------- K2: per-chunk (256 tokens) expert counts ----------------
__global__ void k_count(const int* __restrict__ tokE, int* __restrict__ chunkCnt) {
  __shared__ int c[E];
  if (threadIdx.x < E) c[threadIdx.x] = 0;
  __syncthreads();
  int token = blockIdx.x * 256 + threadIdx.x;
  atomicAdd(&c[tokE[token * 2 + 0]], 1);
  atomicAdd(&c[tokE[token * 2 + 1]], 1);
  __syncthreads();
  if (threadIdx.x < E) chunkCnt[blockIdx.x * E + threadIdx.x] = c[threadIdx.x];
}

// ---------------- K3: scan chunks, stats tail ----------------
__global__ void k_scan(const int* __restrict__ chunkCnt, const float* __restrict__ confPart,
                       int* __restrict__ chunkOff, int* __restrict__ kept,
                       float* __restrict__ outTail, int nConf, int nChunks, int cap, int nTok) {
  if (threadIdx.x < E) {
    int off = 0;
    for (int c = 0; c < nChunks; ++c) {
      chunkOff[c * E + threadIdx.x] = off;
      off += chunkCnt[c * E + threadIdx.x];
    }
    kept[threadIdx.x] = min(off, cap);
  }
  __shared__ float s[256];
  float a = 0.f;
  for (int i = threadIdx.x; i < nConf; i += 256) a += confPart[i];
  s[threadIdx.x] = a;
  __syncthreads();
  for (int st = 128; st > 0; st >>= 1) {
    if (threadIdx.x < st) s[threadIdx.x] += s[threadIdx.x + st];
    __syncthreads();
  }
  if (threadIdx.x == 0) {
    float tot = 0.f, ld[E];
    for (int e = 0; e < E; ++e) { ld[e] = (float)kept[e]; tot += ld[e]; }
    float denom = tot + 1e-8f;
    float loss = 0.f;
    float dist[E];
    for (int e = 0; e < E; ++e) {
      dist[e] = ld[e] / denom;
      loss += dist[e] * logf(dist[e] + 1e-8f);
    }
    outTail[0] = loss;
    for (int e = 0; e < E; ++e) outTail[1 + e] = dist[e];
    outTail[1 + E] = s[0] / (float)nTok;
  }
}

// ---------------- K4: in-order rank assignment + dispatch lists ----------------
__global__ void k_dispatch(const int* __restrict__ tokE, const int* __restrict__ chunkOff,
                           int* __restrict__ expList, int cap) {
  const int lane = threadIdx.x & 63;
  const int wave = threadIdx.x >> 6;
  const int token = blockIdx.x * 256 + threadIdx.x;
  const int e0 = tokE[token * 2 + 0];
  const int e1 = tokE[token * 2 + 1];
  __shared__ int wcnt[4][E];
  unsigned long long lt = (lane == 63) ? 0x7fffffffffffffffull : ((1ull << lane) - 1ull);
  int r0 = 0, r1 = 0;
#pragma unroll
  for (int e = 0; e < E; ++e) {
    unsigned long long b0 = __ballot(e0 == e);
    unsigned long long b1 = __ballot(e1 == e);
    unsigned long long m = b0 | b1;
    if (e0 == e) r0 = __popcll(m & lt);
    if (e1 == e) r1 = __popcll(m & lt);
    if (lane == 0) wcnt[wave][e] = __popcll(m);
  }
  __syncthreads();
  int base0 = chunkOff[blockIdx.x * E + e0];
  int base1 = chunkOff[blockIdx.x * E + e1];
  for (int w = 0; w < wave; ++w) {
    base0 += wcnt[w][e0];
    base1 += wcnt[w][e1];
  }
  int g0 = base0 + r0;
  int g1 = base1 + r1;
  if (g0 < cap) expList[e0 * cap + g0] = token;
  if (g1 < cap) expList[e1 * cap + g1] = token;
}

// ---------------- K-cvt: fp32 [E][R][C] -> bf16 transposed [E][C][R] ----------------
__global__ void k_transpose(const float* __restrict__ in, short* __restrict__ outT,
                            int R, int C) {
  __shared__ float t[32][33];
  const int e = blockIdx.z;
  const int c0 = blockIdx.x * 32, r0 = blockIdx.y * 32;
  const int lx = threadIdx.x & 31, ly = threadIdx.x >> 5;   // 256 thr: ly 0..7
  const float* p = in + ((size_t)e * R + r0) * C + c0;
#pragma unroll
  for (int i = 0; i < 32; i += 8) t[ly + i][lx] = p[(size_t)(ly + i) * C + lx];
  __syncthreads();
  short* q = outT + ((size_t)e * C + c0) * R + r0;
#pragma unroll
  for (int i = 0; i < 32; i += 8) q[(size_t)(ly + i) * R + lx] = f2bf(t[lx][ly + i]);
}

// ---------------- K5: per-expert 2-layer FFN via MFMA ----------------
// W1t: [E][H][D] bf16 ; W2t: [E][D][H] bf16 ; x converted to bf16 in-register.
__global__ __launch_bounds__(256) void k_expert_mfma(
    const float* __restrict__ x, const short* __restrict__ W1t,
    const float* __restrict__ b1, const short* __restrict__ W2t,
    const float* __restrict__ b2, const int* __restrict__ expList,
    const int* __restrict__ kept, float* __restrict__ out, int cap) {
  const int e = blockIdx.y;
  const int cnt = kept[e];
  const int t0 = blockIdx.x * BM;
  if (t0 >= cnt) return;
  const int nt = min(BM, cnt - t0);
  const int lane = threadIdx.x & 63;
  const int wave = threadIdx.x >> 6;

  __shared__ int toks[BM];
  __shared__ short hs[BM][HP];

  if (threadIdx.x < BM) {
    int idx = min(t0 + (int)threadIdx.x, cnt - 1);
    toks[threadIdx.x] = expList[e * cap + idx];
  }
  __syncthreads();

  const int rb = wave * 16;          // this wave's 16-row tile base
  const int rA = rb + (lane & 15);   // A-frag row for this lane
  const int kg = (lane >> 4) * 8;    // A/B-frag k sub-offset

  // ---- layer 1: h[64][128] = relu(x @ W1 + b1), acc 8 n-tiles in VGPRs ----
  const float* xrow = x + (size_t)toks[rA] * D + kg;
  const short* w1p = W1t + ((size_t)e * H + (lane & 15)) * D + kg;
  float4v acc[8];
#pragma unroll
  for (int t = 0; t < 8; ++t) acc[t] = (float4v){0.f, 0.f, 0.f, 0.f};
  for (int ks = 0; ks < 16; ++ks) {
    float4 xa = *(const float4*)(xrow + ks * 32);
    float4 xb_ = *(const float4*)(xrow + ks * 32 + 4);
    short8v a;
    a[0] = f2bf(xa.x); a[1] = f2bf(xa.y); a[2] = f2bf(xa.z); a[3] = f2bf(xa.w);
    a[4] = f2bf(xb_.x); a[5] = f2bf(xb_.y); a[6] = f2bf(xb_.z); a[7] = f2bf(xb_.w);
#pragma unroll
    for (int t = 0; t < 8; ++t) {
      short8v b = *(const short8v*)(w1p + (size_t)t * 16 * D + ks * 32);
      acc[t] = __builtin_amdgcn_mfma_f32_16x16x32_bf16(a, b, acc[t], 0, 0, 0);
    }
  }
#pragma unroll
  for (int t = 0; t < 8; ++t) {
    int col = t * 16 + (lane & 15);
    float bb = b1[e * H + col];
#pragma unroll
    for (int r = 0; r < 4; ++r) {
      int row = rb + (lane >> 4) * 4 + r;
      hs[row][col] = f2bf(fmaxf(acc[t][r] + bb, 0.f));
    }
  }
  __syncthreads();

  // ---- layer 2: y[64][512] = h @ W2 + b2 ; atomic combine ----
  short8v a4[4];
#pragma unroll
  for (int ks = 0; ks < 4; ++ks)
    a4[ks] = *(const short8v*)(&hs[rA][ks * 32 + kg]);

  const short* w2p = W2t + ((size_t)e * D + (lane & 15)) * H + kg;
  const int r0o = (lane >> 4) * 4;
#pragma unroll 2
  for (int t = 0; t < 32; ++t) {
    float4v yacc = (float4v){0.f, 0.f, 0.f, 0.f};
#pragma unroll
    for (int ks = 0; ks < 4; ++ks) {
      short8v b = *(const short8v*)(w2p + (size_t)t * 16 * H + ks * 32);
      yacc = __builtin_amdgcn_mfma_f32_16x16x32_bf16(a4[ks], b, yacc, 0, 0, 0);
    }
    int col = t * 16 + (lane & 15);
    float bb = b2[e * D + col];
#pragma unroll
    for (int r = 0; r < 4; ++r) {
      int row = rb + r0o + r;
      if (row < nt)
        atomicAdd(&out[(size_t)toks[row] * D + col], yacc[r] + bb);
    }
  }
}

extern "C" void kernel_launch(void* const* d_in, const int* in_sizes, int n_in,
                              void* d_out, int out_size, void* d_ws, size_t ws_size,
                              hipStream_t stream) {
  const float* x  = (const float*)d_in[0];
  const float* Wr = (const float*)d_in[1];
  const float* br = (const float*)d_in[2];
  const float* W1 = (const float*)d_in[3];
  const float* b1 = (const float*)d_in[4];
  const float* W2 = (const float*)d_in[5];
  const float* b2 = (const float*)d_in[6];
  float* out = (float*)d_out;

  const int N = in_sizes[0] / D;                 // 32768
  const int cap = (int)(1.25f * (float)(N / E)); // 5120
  const int chunks = N / 256;                    // 128

  int* tokE = (int*)d_ws;
  float* confPart = (float*)(tokE + (size_t)N * 2);
  int* chunkCnt = (int*)(confPart + N / 4);
  int* chunkOff = chunkCnt + chunks * E;
  int* kept = chunkOff + chunks * E;
  int* expList = kept + E;
  short* W1t = (short*)(expList + (size_t)E * cap);          // [E][H][D]
  short* W2t = W1t + (size_t)E * H * D;                      // [E][D][H]

  (void)hipMemsetAsync(d_out, 0, (size_t)N * D * sizeof(float), stream);

  // weight transposes (tiny, L2-resident afterwards)
  k_transpose<<<dim3(H / 32, D / 32, E), 256, 0, stream>>>(W1, W1t, D, H);
  k_transpose<<<dim3(D / 32, H / 32, E), 256, 0, stream>>>(W2, W2t, H, D);

  k_router<<<N / 4, 256, 0, stream>>>(x, Wr, br, tokE, confPart);
  k_count<<<chunks, 256, 0, stream>>>(tokE, chunkCnt);
  k_scan<<<1, 256, 0, stream>>>(chunkCnt, confPart, chunkOff, kept,
                                out + (size_t)N * D, N / 4, chunks, cap, N);
  k_dispatch<<<chunks, 256, 0, stream>>>(tokE, chunkOff, expList, cap);

  const int tiles = (cap + BM - 1) / BM;
  dim3 g5(tiles, E);
  k_expert_mfma<<<g5, 256, 0, stream>>>(x, W1t, b1, W2t, b2, expList, kept, out, cap);
}

// Round 4
// 208.178 us; speedup vs baseline: 1.5763x; 1.1714x over previous
//
#include <hip/hip_runtime.h>

#define D 512
#define E 8
#define H 128
#define BM 64
#define HP 136   // padded LDS row stride for h (shorts)

typedef __attribute__((ext_vector_type(8))) short short8v;
typedef __attribute__((ext_vector_type(4))) short short4v;
typedef __attribute__((ext_vector_type(4))) float float4v;

__device__ inline short f2bf(float f) {
  union { float f; unsigned u; } v; v.f = f;
  unsigned r = v.u + 0x7fffu + ((v.u >> 16) & 1u);   // RNE
  return (short)(r >> 16);
}
__device__ inline float bf2f(short s) {
  union { unsigned u; float f; } v;
  v.u = ((unsigned)(unsigned short)s) << 16;
  return v.f;
}

// ---------------- K1: router — one wave per token (fp32 exact) ----------------
__global__ void k_router(const float* __restrict__ x, const float* __restrict__ Wr,
                         const float* __restrict__ br, int* __restrict__ tokE,
                         float* __restrict__ confPart) {
  const int lane = threadIdx.x & 63;
  const int wave = threadIdx.x >> 6;
  const int token = blockIdx.x * 4 + wave;

  float wr[8][8];
  const float4* wrp = reinterpret_cast<const float4*>(Wr) + lane * 16;
#pragma unroll
  for (int j = 0; j < 8; ++j) {
    float4 a = wrp[j * 2 + 0];
    float4 b = wrp[j * 2 + 1];
    wr[j][0] = a.x; wr[j][1] = a.y; wr[j][2] = a.z; wr[j][3] = a.w;
    wr[j][4] = b.x; wr[j][5] = b.y; wr[j][6] = b.z; wr[j][7] = b.w;
  }

  const float4* xp = reinterpret_cast<const float4*>(x + (size_t)token * D + lane * 8);
  float4 x0 = xp[0], x1 = xp[1];
  float xv[8] = {x0.x, x0.y, x0.z, x0.w, x1.x, x1.y, x1.z, x1.w};

  float acc[E] = {0, 0, 0, 0, 0, 0, 0, 0};
#pragma unroll
  for (int j = 0; j < 8; ++j)
#pragma unroll
    for (int e = 0; e < E; ++e)
      acc[e] += xv[j] * wr[j][e];

#pragma unroll
  for (int m = 1; m < 64; m <<= 1)
#pragma unroll
    for (int e = 0; e < E; ++e)
      acc[e] += __shfl_xor(acc[e], m, 64);

  __shared__ float cf[4];
  if (lane == 0) {
#pragma unroll
    for (int e = 0; e < E; ++e) acc[e] += br[e];
    int e0 = 0; float v0 = acc[0];
#pragma unroll
    for (int e = 1; e < E; ++e) if (acc[e] > v0) { v0 = acc[e]; e0 = e; }
    int e1 = -1; float v1 = -1e30f;
#pragma unroll
    for (int e = 0; e < E; ++e) if (e != e0 && acc[e] > v1) { v1 = acc[e]; e1 = e; }
    tokE[token * 2 + 0] = e0;
    tokE[token * 2 + 1] = e1;
    cf[wave] = v0;
  }
  __syncthreads();
  if (threadIdx.x == 0) confPart[blockIdx.x] = cf[0] + cf[1] + cf[2] + cf[3];
}

// ---------------- K2: per-chunk (256 tokens) expert counts ----------------
__global__ void k_count(const int* __restrict__ tokE, int* __restrict__ chunkCnt) {
  __shared__ int c[E];
  if (threadIdx.x < E) c[threadIdx.x] = 0;
  __syncthreads();
  int token = blockIdx.x * 256 + threadIdx.x;
  atomicAdd(&c[tokE[token * 2 + 0]], 1);
  atomicAdd(&c[tokE[token * 2 + 1]], 1);
  __syncthreads();
  if (threadIdx.x < E) chunkCnt[blockIdx.x * E + threadIdx.x] = c[threadIdx.x];
}

// ---------------- K3: wave-parallel scan (512 thr, wave e = expert e) + stats ----------------
__global__ void k_scan(const int* __restrict__ chunkCnt, const float* __restrict__ confPart,
                       int* __restrict__ chunkOff, int* __restrict__ kept,
                       float* __restrict__ outTail, int nConf, int cap, int nTok) {
  const int lane = threadIdx.x & 63;
  const int e = threadIdx.x >> 6;         // 8 waves, one per expert (nChunks == 128)
  __shared__ int keptS[E];

  int v0 = chunkCnt[lane * E + e];
  int v1 = chunkCnt[(64 + lane) * E + e];
  int s0 = v0, s1 = v1;
#pragma unroll
  for (int off = 1; off < 64; off <<= 1) {
    int t0 = __shfl_up(s0, off, 64);
    int t1 = __shfl_up(s1, off, 64);
    if (lane >= off) { s0 += t0; s1 += t1; }
  }
  int tot0 = __shfl(s0, 63, 64);
  int total = tot0 + __shfl(s1, 63, 64);
  chunkOff[lane * E + e] = s0 - v0;
  chunkOff[(64 + lane) * E + e] = tot0 + s1 - v1;
  if (lane == 0) {
    int k = min(total, cap);
    kept[e] = k;
    keptS[e] = k;
  }

  __shared__ float s[512];
  float a = 0.f;
  for (int i = threadIdx.x; i < nConf; i += 512) a += confPart[i];
  s[threadIdx.x] = a;
  __syncthreads();
  for (int st = 256; st > 0; st >>= 1) {
    if (threadIdx.x < st) s[threadIdx.x] += s[threadIdx.x + st];
    __syncthreads();
  }
  if (threadIdx.x == 0) {
    float tot = 0.f, ld[E];
    for (int i = 0; i < E; ++i) { ld[i] = (float)keptS[i]; tot += ld[i]; }
    float denom = tot + 1e-8f;
    float loss = 0.f;
    for (int i = 0; i < E; ++i) {
      float dist = ld[i] / denom;
      loss += dist * logf(dist + 1e-8f);
      outTail[1 + i] = dist;
    }
    outTail[0] = loss;
    outTail[1 + E] = s[0] / (float)nTok;
  }
}

// ---------------- K4: rank assignment + dispatch lists + token->slot map ----------------
__global__ void k_dispatch(const int* __restrict__ tokE, const int* __restrict__ chunkOff,
                           int* __restrict__ expList, int2* __restrict__ tokSlot, int cap) {
  const int lane = threadIdx.x & 63;
  const int wave = threadIdx.x >> 6;
  const int token = blockIdx.x * 256 + threadIdx.x;
  const int e0 = tokE[token * 2 + 0];
  const int e1 = tokE[token * 2 + 1];
  __shared__ int wcnt[4][E];
  unsigned long long lt = (lane == 63) ? 0x7fffffffffffffffull : ((1ull << lane) - 1ull);
  int r0 = 0, r1 = 0;
#pragma unroll
  for (int e = 0; e < E; ++e) {
    unsigned long long b0 = __ballot(e0 == e);
    unsigned long long b1 = __ballot(e1 == e);
    unsigned long long m = b0 | b1;
    if (e0 == e) r0 = __popcll(m & lt);
    if (e1 == e) r1 = __popcll(m & lt);
    if (lane == 0) wcnt[wave][e] = __popcll(m);
  }
  __syncthreads();
  int base0 = chunkOff[blockIdx.x * E + e0];
  int base1 = chunkOff[blockIdx.x * E + e1];
  for (int w = 0; w < wave; ++w) {
    base0 += wcnt[w][e0];
    base1 += wcnt[w][e1];
  }
  int g0 = base0 + r0;
  int g1 = base1 + r1;
  if (g0 < cap) expList[e0 * cap + g0] = token;
  if (g1 < cap) expList[e1 * cap + g1] = token;
  tokSlot[token] = make_int2(g0 < cap ? e0 * cap + g0 : -1,
                             g1 < cap ? e1 * cap + g1 : -1);
}

// ---------------- K-cvt: fp32 [E][R][C] -> bf16 transposed [E][C][R] ----------------
__global__ void k_transpose(const float* __restrict__ in, short* __restrict__ outT,
                            int R, int C) {
  __shared__ float t[32][33];
  const int e = blockIdx.z;
  const int c0 = blockIdx.x * 32, r0 = blockIdx.y * 32;
  const int lx = threadIdx.x & 31, ly = threadIdx.x >> 5;
  const float* p = in + ((size_t)e * R + r0) * C + c0;
#pragma unroll
  for (int i = 0; i < 32; i += 8) t[ly + i][lx] = p[(size_t)(ly + i) * C + lx];
  __syncthreads();
  short* q = outT + ((size_t)e * C + c0) * R + r0;
#pragma unroll
  for (int i = 0; i < 32; i += 8) q[(size_t)(ly + i) * R + lx] = f2bf(t[lx][ly + i]);
}

// ---------------- K5: per-expert FFN via MFMA (swapped operands), bf16 y scratch ----------------
// W1t: [E][H][D] bf16 ; W2t: [E][D][H] bf16
// layer1: C[m=hcol][n=token] = mfma(A=W1 frag, B=x frag)  -> packed short4 into LDS h
// layer2: C[m=dcol][n=token] = mfma(A=W2 frag, B=h frag)  -> packed short4 into yscr
__global__ __launch_bounds__(256) void k_expert_mfma(
    const float* __restrict__ x, const short* __restrict__ W1t,
    const float* __restrict__ b1, const short* __restrict__ W2t,
    const float* __restrict__ b2, const int* __restrict__ expList,
    const int* __restrict__ kept, short* __restrict__ yscr, int cap) {
  const int e = blockIdx.y;
  const int cnt = kept[e];
  const int t0 = blockIdx.x * BM;
  if (t0 >= cnt) return;
  const int lane = threadIdx.x & 63;
  const int wave = threadIdx.x >> 6;
  const int rb = wave * 16;
  const int n15 = lane & 15;          // token index within wave tile (B-frag n)
  const int grp = lane >> 4;          // k sub-group
  const int kg = grp * 8;

  __shared__ int toks[BM];
  __shared__ short hs[BM][HP];

  if (threadIdx.x < BM) {
    int idx = min(t0 + (int)threadIdx.x, cnt - 1);
    toks[threadIdx.x] = expList[e * cap + idx];
  }
  __syncthreads();

  // ---- load & convert all 16 x K-fragments up front (independent loads) ----
  const float* xrow = x + (size_t)toks[rb + n15] * D + kg;
  short8v xf[16];
#pragma unroll
  for (int ks = 0; ks < 16; ++ks) {
    float4 a = *(const float4*)(xrow + ks * 32);
    float4 b = *(const float4*)(xrow + ks * 32 + 4);
    short8v f;
    f[0] = f2bf(a.x); f[1] = f2bf(a.y); f[2] = f2bf(a.z); f[3] = f2bf(a.w);
    f[4] = f2bf(b.x); f[5] = f2bf(b.y); f[6] = f2bf(b.z); f[7] = f2bf(b.w);
    xf[ks] = f;
  }

  // ---- layer 1: A = W1 rows (hcol), 8 m-tiles ----
  const short* w1p = W1t + ((size_t)e * H + n15) * D + kg;
  float4v acc[8];
#pragma unroll
  for (int t = 0; t < 8; ++t) acc[t] = (float4v){0.f, 0.f, 0.f, 0.f};
#pragma unroll
  for (int ks = 0; ks < 16; ++ks) {
#pragma unroll
    for (int t = 0; t < 8; ++t) {
      short8v a = *(const short8v*)(w1p + (size_t)t * 16 * D + ks * 32);
      acc[t] = __builtin_amdgcn_mfma_f32_16x16x32_bf16(a, xf[ks], acc[t], 0, 0, 0);
    }
  }
#pragma unroll
  for (int t = 0; t < 8; ++t) {
    float4 bb = *(const float4*)(b1 + e * H + t * 16 + grp * 4);
    short4v p;
    p[0] = f2bf(fmaxf(acc[t][0] + bb.x, 0.f));
    p[1] = f2bf(fmaxf(acc[t][1] + bb.y, 0.f));
    p[2] = f2bf(fmaxf(acc[t][2] + bb.z, 0.f));
    p[3] = f2bf(fmaxf(acc[t][3] + bb.w, 0.f));
    *(short4v*)(&hs[rb + n15][t * 16 + grp * 4]) = p;
  }
  __syncthreads();

  // ---- layer 2: A = W2 rows (dcol), B = h frags from LDS ----
  short8v a4[4];
#pragma unroll
  for (int ks = 0; ks < 4; ++ks)
    a4[ks] = *(const short8v*)(&hs[rb + n15][ks * 32 + kg]);

  const short* w2p = W2t + ((size_t)e * D + n15) * H + kg;
  short* yrow = yscr + ((size_t)(e * cap + t0 + rb + n15)) * D;
#pragma unroll 4
  for (int t = 0; t < 32; ++t) {
    float4v y = (float4v){0.f, 0.f, 0.f, 0.f};
#pragma unroll
    for (int ks = 0; ks < 4; ++ks) {
      short8v a = *(const short8v*)(w2p + (size_t)t * 16 * H + ks * 32);
      y = __builtin_amdgcn_mfma_f32_16x16x32_bf16(a, a4[ks], y, 0, 0, 0);
    }
    float4 bb = *(const float4*)(b2 + e * D + t * 16 + grp * 4);
    short4v p;
    p[0] = f2bf(y[0] + bb.x);
    p[1] = f2bf(y[1] + bb.y);
    p[2] = f2bf(y[2] + bb.z);
    p[3] = f2bf(y[3] + bb.w);
    *(short4v*)(yrow + t * 16 + grp * 4) = p;
  }
}

// ---------------- K6: combine — out[token] = sum of kept slots (or 0) ----------------
__global__ void k_combine(const short* __restrict__ yscr, const int2* __restrict__ tokSlot,
                          float* __restrict__ out) {
  const int idx = blockIdx.x * 256 + threadIdx.x;   // one float4 per thread
  const int token = idx >> 7;                       // 128 float4 per row
  const int c4 = idx & 127;
  int2 sl = tokSlot[token];
  float4 r = make_float4(0.f, 0.f, 0.f, 0.f);
  if (sl.x >= 0) {
    short4v y = *(const short4v*)(yscr + (size_t)sl.x * D + c4 * 4);
    r.x += bf2f(y[0]); r.y += bf2f(y[1]); r.z += bf2f(y[2]); r.w += bf2f(y[3]);
  }
  if (sl.y >= 0) {
    short4v y = *(const short4v*)(yscr + (size_t)sl.y * D + c4 * 4);
    r.x += bf2f(y[0]); r.y += bf2f(y[1]); r.z += bf2f(y[2]); r.w += bf2f(y[3]);
  }
  reinterpret_cast<float4*>(out)[idx] = r;
}

extern "C" void kernel_launch(void* const* d_in, const int* in_sizes, int n_in,
                              void* d_out, int out_size, void* d_ws, size_t ws_size,
                              hipStream_t stream) {
  const float* x  = (const float*)d_in[0];
  const float* Wr = (const float*)d_in[1];
  const float* br = (const float*)d_in[2];
  const float* W1 = (const float*)d_in[3];
  const float* b1 = (const float*)d_in[4];
  const float* W2 = (const float*)d_in[5];
  const float* b2 = (const float*)d_in[6];
  float* out = (float*)d_out;

  const int N = in_sizes[0] / D;                 // 32768
  const int cap = (int)(1.25f * (float)(N / E)); // 5120
  const int chunks = N / 256;                    // 128

  int* tokE = (int*)d_ws;                                    // N*2
  float* confPart = (float*)(tokE + (size_t)N * 2);          // N/4
  int* chunkCnt = (int*)(confPart + N / 4);                  // chunks*E
  int* chunkOff = chunkCnt + chunks * E;                     // chunks*E
  int* kept = chunkOff + chunks * E;                         // E
  int2* tokSlot = (int2*)(kept + E);                         // N int2
  int* expList = (int*)(tokSlot + N);                        // E*cap
  short* W1t = (short*)(expList + (size_t)E * cap);          // [E][H][D]
  short* W2t = W1t + (size_t)E * H * D;                      // [E][D][H]
  short* yscr = W2t + (size_t)E * H * D;                     // [E*cap][D] bf16

  k_transpose<<<dim3(H / 32, D / 32, E), 256, 0, stream>>>(W1, W1t, D, H);
  k_transpose<<<dim3(D / 32, H / 32, E), 256, 0, stream>>>(W2, W2t, H, D);

  k_router<<<N / 4, 256, 0, stream>>>(x, Wr, br, tokE, confPart);
  k_count<<<chunks, 256, 0, stream>>>(tokE, chunkCnt);
  k_scan<<<1, 512, 0, stream>>>(chunkCnt, confPart, chunkOff, kept,
                                out + (size_t)N * D, N / 4, cap, N);
  k_dispatch<<<chunks, 256, 0, stream>>>(tokE, chunkOff, expList, tokSlot, cap);

  const int tiles = (cap + BM - 1) / BM;
  dim3 g5(tiles, E);
  k_expert_mfma<<<g5, 256, 0, stream>>>(x, W1t, b1, W2t, b2, expList, kept, yscr, cap);

  k_combine<<<(N * D / 4) / 256, 256, 0, stream>>>(yscr, tokSlot, out);
}